// Round 1
// baseline (823.999 us; speedup 1.0000x reference)
//
#include <hip/hip_runtime.h>

// PTDNet-GCN eval forward.
// Key simplifications vs reference:
//  - L=2 hard-concrete samples are identical in eval path -> compute once.
//  - Edge MLP factors: logit[e] = s1[row[e]] + s2[col[e]] + att_b, with
//    s1[n] = relu(x[n]@nb_w+nb_b)@aw[:16], s2[n] = relu(x[n]@self_w+self_b)@aw[16:].
//  - CSR (built per launch from row/col) makes rowsum + aggregation atomic-free.

__global__ __launch_bounds__(256) void k_hist(const int* __restrict__ row,
                                              int* __restrict__ counts, int E) {
  int e = blockIdx.x * 256 + threadIdx.x;
  if (e < E) atomicAdd(&counts[row[e]], 1);
}

__global__ __launch_bounds__(256) void k_blocksum(const int* __restrict__ counts,
                                                  int* __restrict__ bsum, int N) {
  __shared__ int sdata[256];
  int base = blockIdx.x * 1024;
  int s = 0;
#pragma unroll
  for (int k = 0; k < 4; k++) {
    int i = base + k * 256 + threadIdx.x;
    if (i < N) s += counts[i];
  }
  sdata[threadIdx.x] = s;
  __syncthreads();
  for (int off = 128; off > 0; off >>= 1) {
    if (threadIdx.x < off) sdata[threadIdx.x] += sdata[threadIdx.x + off];
    __syncthreads();
  }
  if (threadIdx.x == 0) bsum[blockIdx.x] = sdata[0];
}

__global__ __launch_bounds__(128) void k_scanpart(const int* __restrict__ bsum,
                                                  int* __restrict__ boff, int NB,
                                                  int* __restrict__ row_start, int N) {
  __shared__ int s[129];
  int t = threadIdx.x;
  s[t] = (t < NB) ? bsum[t] : 0;
  __syncthreads();
  if (t == 0) {
    int r = 0;
    for (int b = 0; b < NB; b++) { int v = s[b]; s[b] = r; r += v; }
    row_start[N] = r;  // == E
  }
  __syncthreads();
  if (t < NB) boff[t] = s[t];
}

__global__ __launch_bounds__(256) void k_scanblk(const int* __restrict__ counts,
                                                 const int* __restrict__ boff,
                                                 int* __restrict__ row_start, int N) {
  __shared__ int warp_sums[4];
  int tid = threadIdx.x, lane = tid & 63, wid = tid >> 6;
  int base = blockIdx.x * 1024;
  int i0 = base + tid * 4;
  int c0, c1, c2, c3;
  if (i0 + 3 < N) {
    int4 v = *(const int4*)(counts + i0);
    c0 = v.x; c1 = v.y; c2 = v.z; c3 = v.w;
  } else {
    c0 = (i0 + 0 < N) ? counts[i0 + 0] : 0;
    c1 = (i0 + 1 < N) ? counts[i0 + 1] : 0;
    c2 = (i0 + 2 < N) ? counts[i0 + 2] : 0;
    c3 = (i0 + 3 < N) ? counts[i0 + 3] : 0;
  }
  int s = c0 + c1 + c2 + c3;
  int incl = s;
#pragma unroll
  for (int off = 1; off < 64; off <<= 1) {
    int v = __shfl_up(incl, off);
    if (lane >= off) incl += v;
  }
  if (lane == 63) warp_sums[wid] = incl;
  __syncthreads();
  int pre = 0;
  for (int w = 0; w < wid; w++) pre += warp_sums[w];
  int run = boff[blockIdx.x] + pre + incl - s;  // exclusive prefix for this thread
  if (i0 + 0 < N) row_start[i0 + 0] = run; run += c0;
  if (i0 + 1 < N) row_start[i0 + 1] = run; run += c1;
  if (i0 + 2 < N) row_start[i0 + 2] = run; run += c2;
  if (i0 + 3 < N) row_start[i0 + 3] = run;
}

__global__ __launch_bounds__(256) void k_scatter(const int* __restrict__ row,
                                                 const int* __restrict__ col,
                                                 const int* __restrict__ row_start,
                                                 int* __restrict__ cursor,
                                                 int* __restrict__ csr_col, int E) {
  int e = blockIdx.x * 256 + threadIdx.x;
  if (e < E) {
    int r = row[e];
    int pos = row_start[r] + atomicAdd(&cursor[r], 1);
    csr_col[pos] = col[e];
  }
}

// Per-node attention scalars: s1[n] = relu(x[n]@W1+b1).aw[0:16],
// s2[n] = relu(x[n]@W2+b2).aw[16:32] + att_b  (att_b folded into s2).
__global__ __launch_bounds__(256) void k_proj(const float* __restrict__ X,
                                              const float* __restrict__ W1,
                                              const float* __restrict__ b1,
                                              const float* __restrict__ W2,
                                              const float* __restrict__ b2,
                                              const float* __restrict__ aw,
                                              const float* __restrict__ attb,
                                              float* __restrict__ s1,
                                              float* __restrict__ s2, int N) {
  int n = blockIdx.x * 256 + threadIdx.x;
  if (n >= N) return;
  float a1[16], a2[16];
#pragma unroll
  for (int h = 0; h < 16; h++) { a1[h] = b1[h]; a2[h] = b2[h]; }
  const float4* xr = (const float4*)(X + (size_t)n * 128);
  for (int d4 = 0; d4 < 32; ++d4) {
    float4 xv = xr[d4];
#pragma unroll
    for (int q = 0; q < 4; q++) {
      float xs = ((const float*)&xv)[q];
      int d = d4 * 4 + q;
      const float4* w1r = (const float4*)(W1 + d * 16);
      const float4* w2r = (const float4*)(W2 + d * 16);
#pragma unroll
      for (int g = 0; g < 4; ++g) {
        float4 wa = w1r[g], wb = w2r[g];
        a1[g * 4 + 0] += xs * wa.x; a1[g * 4 + 1] += xs * wa.y;
        a1[g * 4 + 2] += xs * wa.z; a1[g * 4 + 3] += xs * wa.w;
        a2[g * 4 + 0] += xs * wb.x; a2[g * 4 + 1] += xs * wb.y;
        a2[g * 4 + 2] += xs * wb.z; a2[g * 4 + 3] += xs * wb.w;
      }
    }
  }
  float r1 = 0.f, r2 = 0.f;
#pragma unroll
  for (int h = 0; h < 16; h++) {
    r1 += fmaxf(a1[h], 0.f) * aw[h];
    r2 += fmaxf(a2[h], 0.f) * aw[16 + h];
  }
  s1[n] = r1;
  s2[n] = r2 + attb[0];
}

// One wave per row: per-edge mask (hard-concrete eval gate) + row degree -> dis.
__global__ __launch_bounds__(256) void k_mask(const int* __restrict__ row_start,
                                              const int* __restrict__ csr_col,
                                              const float* __restrict__ s1,
                                              const float* __restrict__ s2,
                                              float* __restrict__ mask_csr,
                                              float* __restrict__ dis, int N) {
  int lane = threadIdx.x & 63, wid = threadIdx.x >> 6;
  int r = blockIdx.x * 4 + wid;
  if (r >= N) return;
  int start = row_start[r], end = row_start[r + 1];
  float s1r = s1[r];
  float sum = 0.f;
  for (int p = start + lane; p < end; p += 64) {
    int c = csr_col[p];
    float logit = s1r + s2[c];
    float g = 1.f / (1.f + __expf(-logit));
    float m = fminf(fmaxf(fmaf(g, 1.2f, -0.1f), 0.f), 1.f);  // ZETA-GAMMA=1.2, GAMMA=-0.1
    mask_csr[p] = m;
    sum += m;
  }
#pragma unroll
  for (int off = 32; off > 0; off >>= 1) sum += __shfl_down(sum, off);
  if (lane == 0) dis[r] = rsqrtf(sum + 1.0f);  // +1 from the identity diag; result <=1 so clip is inert
}

// H = X @ W  (f32 vector ALU; no fp32 MFMA on CDNA4). 64-row tile, W staged in LDS.
template <int DOUT>
__global__ __launch_bounds__(256) void k_gemm(const float* __restrict__ X,
                                              const float* __restrict__ W,
                                              float* __restrict__ H, int N) {
  constexpr int CPT = DOUT / 4;  // cols per thread
  __shared__ float Ws[64 * DOUT];
  __shared__ float Xs[64][68];  // +4 pad: bank-spread + keeps 16B row alignment
  int tid = threadIdx.x;
  int n0 = blockIdx.x * 64;
  int nl = tid >> 2, cq = tid & 3;
  int nvalid = min(64, N - n0);
  float acc[CPT];
#pragma unroll
  for (int j = 0; j < CPT; j++) acc[j] = 0.f;
  for (int dt = 0; dt < 2; ++dt) {
    __syncthreads();
    const float4* Wg = (const float4*)(W + dt * 64 * DOUT);
    float4* Ws4 = (float4*)Ws;
    for (int i = tid; i < 64 * DOUT / 4; i += 256) Ws4[i] = Wg[i];
    for (int i = tid; i < nvalid * 16; i += 256) {
      int rl = i >> 4, d4 = i & 15;
      float4 v = *(const float4*)(X + (size_t)(n0 + rl) * 128 + dt * 64 + d4 * 4);
      Xs[rl][d4 * 4 + 0] = v.x; Xs[rl][d4 * 4 + 1] = v.y;
      Xs[rl][d4 * 4 + 2] = v.z; Xs[rl][d4 * 4 + 3] = v.w;
    }
    __syncthreads();
#pragma unroll 8
    for (int d = 0; d < 64; ++d) {
      float xv = Xs[nl][d];
#pragma unroll
      for (int jj = 0; jj < CPT / 4; ++jj) {
        const float4 w = *(const float4*)&Ws[d * DOUT + (cq + jj * 4) * 4];
        acc[jj * 4 + 0] = fmaf(xv, w.x, acc[jj * 4 + 0]);
        acc[jj * 4 + 1] = fmaf(xv, w.y, acc[jj * 4 + 1]);
        acc[jj * 4 + 2] = fmaf(xv, w.z, acc[jj * 4 + 2]);
        acc[jj * 4 + 3] = fmaf(xv, w.w, acc[jj * 4 + 3]);
      }
    }
  }
  int n = n0 + nl;
  if (n < N) {
    float* Hr = H + (size_t)n * DOUT;
#pragma unroll
    for (int jj = 0; jj < CPT / 4; jj++) {
      float4 o;
      o.x = acc[jj * 4 + 0]; o.y = acc[jj * 4 + 1];
      o.z = acc[jj * 4 + 2]; o.w = acc[jj * 4 + 3];
      *(float4*)&Hr[(cq + jj * 4) * 4] = o;
    }
  }
}

// One wave per row: out[r] = act( dis[r]*sum_e mask*dis[col]*H[col] + dis[r]^2*H[r] ).
template <int DOUT, bool RELU>
__global__ __launch_bounds__(256) void k_agg(const int* __restrict__ row_start,
                                             const int* __restrict__ csr_col,
                                             const float* __restrict__ mask_csr,
                                             const float* __restrict__ dis,
                                             const float* __restrict__ H,
                                             float* __restrict__ out, int N) {
  int lane = threadIdx.x & 63, wid = threadIdx.x >> 6;
  int r = blockIdx.x * 4 + wid;
  if (r >= N) return;
  int start = row_start[r], end = row_start[r + 1];
  float dr = dis[r];
  if constexpr (DOUT == 128) {
    float ax = 0.f, ay = 0.f;
    for (int p = start; p < end; p++) {
      int c = csr_col[p];
      float v = mask_csr[p] * dis[c];
      float2 hv = *(const float2*)(H + (size_t)c * 128 + lane * 2);
      ax = fmaf(v, hv.x, ax);
      ay = fmaf(v, hv.y, ay);
    }
    float2 hr = *(const float2*)(H + (size_t)r * 128 + lane * 2);
    float ox = dr * ax + dr * dr * hr.x;
    float oy = dr * ay + dr * dr * hr.y;
    if (RELU) { ox = fmaxf(ox, 0.f); oy = fmaxf(oy, 0.f); }
    *(float2*)(out + (size_t)r * 128 + lane * 2) = make_float2(ox, oy);
  } else {
    float a = 0.f;
    for (int p = start; p < end; p++) {
      int c = csr_col[p];
      float v = mask_csr[p] * dis[c];
      a = fmaf(v, H[(size_t)c * DOUT + lane], a);
    }
    float o = dr * a + dr * dr * H[(size_t)r * DOUT + lane];
    if (RELU) o = fmaxf(o, 0.f);
    out[(size_t)r * DOUT + lane] = o;
  }
}

extern "C" void kernel_launch(void* const* d_in, const int* in_sizes, int n_in,
                              void* d_out, int out_size, void* d_ws, size_t ws_size,
                              hipStream_t stream) {
  const float* x      = (const float*)d_in[0];
  const int*   row    = (const int*)d_in[1];
  const int*   col    = (const int*)d_in[2];
  const float* nb_w   = (const float*)d_in[3];
  const float* nb_b   = (const float*)d_in[4];
  const float* self_w = (const float*)d_in[5];
  const float* self_b = (const float*)d_in[6];
  const float* att_w  = (const float*)d_in[7];
  const float* att_b  = (const float*)d_in[8];
  const float* w0     = (const float*)d_in[9];
  const float* w1     = (const float*)d_in[10];
  float* out = (float*)d_out;

  const int N = in_sizes[0] / 128;
  const int E = in_sizes[1];

  char* p = (char*)d_ws;
  auto alloc = [&](size_t bytes) -> void* {
    void* q = (void*)p;
    p += (bytes + 255) & ~(size_t)255;
    return q;
  };
  int*   counts    = (int*)alloc((size_t)N * 4);        // also reused as scatter cursor
  int*   row_start = (int*)alloc((size_t)(N + 1) * 4);
  int*   bsum      = (int*)alloc(512);
  int*   boff      = (int*)alloc(512);
  int*   csr_col   = (int*)alloc((size_t)E * 4);
  float* mask_csr  = (float*)alloc((size_t)E * 4);
  float* s1        = (float*)alloc((size_t)N * 4);
  float* s2        = (float*)alloc((size_t)N * 4);
  float* dis       = (float*)alloc((size_t)N * 4);
  float* h         = (float*)alloc((size_t)N * 128 * 4);
  float* X1        = (float*)alloc((size_t)N * 128 * 4);

  const int NB = (N + 1023) / 1024;  // 98 for N=100000 (must be <=128)
  const int gE = (E + 255) / 256;
  const int gw = (N + 3) / 4;    // wave-per-row kernels
  const int gp = (N + 255) / 256;
  const int gg = (N + 63) / 64;

  // ---- CSR build (row/col are launch-invariant inputs, but ws is re-poisoned) ----
  hipMemsetAsync(counts, 0, (size_t)N * 4, stream);
  k_hist<<<gE, 256, 0, stream>>>(row, counts, E);
  k_blocksum<<<NB, 256, 0, stream>>>(counts, bsum, N);
  k_scanpart<<<1, 128, 0, stream>>>(bsum, boff, NB, row_start, N);
  k_scanblk<<<NB, 256, 0, stream>>>(counts, boff, row_start, N);
  hipMemsetAsync(counts, 0, (size_t)N * 4, stream);
  k_scatter<<<gE, 256, 0, stream>>>(row, col, row_start, counts, csr_col, E);

  // ---- layer 0: din=128, dout=128, relu ----
  k_proj<<<gp, 256, 0, stream>>>(x, nb_w, nb_b, self_w, self_b, att_w, att_b, s1, s2, N);
  k_mask<<<gw, 256, 0, stream>>>(row_start, csr_col, s1, s2, mask_csr, dis, N);
  k_gemm<128><<<gg, 256, 0, stream>>>(x, w0, h, N);
  k_agg<128, true><<<gw, 256, 0, stream>>>(row_start, csr_col, mask_csr, dis, h, X1, N);

  // ---- layer 1: din=128, dout=64, identity ----
  k_proj<<<gp, 256, 0, stream>>>(X1, nb_w + 2048, nb_b + 16, self_w + 2048, self_b + 16,
                                 att_w + 32, att_b + 1, s1, s2, N);
  k_mask<<<gw, 256, 0, stream>>>(row_start, csr_col, s1, s2, mask_csr, dis, N);
  k_gemm<64><<<gg, 256, 0, stream>>>(X1, w1, h, N);
  k_agg<64, false><<<gw, 256, 0, stream>>>(row_start, csr_col, mask_csr, dis, h, out, N);
}

// Round 3
// 645.751 us; speedup vs baseline: 1.2760x; 1.2760x over previous
//
#include <hip/hip_runtime.h>

// PTDNet-GCN eval forward.
//  - L=2 hard-concrete samples identical in eval -> compute once.
//  - Edge MLP factors into per-node scalars s1/s2.
//  - CSR build -> atomic-free rowsum + aggregation.
//  - H stored as bf16x2, pre-scaled by dis[c] (gemm epilogue): halves gather bytes,
//    removes per-edge dis gather, self term becomes a plain summand.

__device__ inline float bf_lo(uint32_t u) { return __uint_as_float(u << 16); }
__device__ inline float bf_hi(uint32_t u) { return __uint_as_float(u & 0xffff0000u); }
__device__ inline uint32_t pack_bf2(float x, float y) {  // RTNE
  uint32_t bx = __float_as_uint(x), by = __float_as_uint(y);
  uint32_t rx = (bx + 0x7fffu + ((bx >> 16) & 1u)) >> 16;
  uint32_t ry = (by + 0x7fffu + ((by >> 16) & 1u)) >> 16;
  return (rx & 0xffffu) | (ry << 16);
}

__global__ __launch_bounds__(256) void k_hist(const int* __restrict__ row,
                                              int* __restrict__ counts, int E) {
  int e = blockIdx.x * 256 + threadIdx.x;
  if (e < E) atomicAdd(&counts[row[e]], 1);
}

__global__ __launch_bounds__(256) void k_blocksum(const int* __restrict__ counts,
                                                  int* __restrict__ bsum, int N) {
  __shared__ int sdata[256];
  int base = blockIdx.x * 1024;
  int s = 0;
#pragma unroll
  for (int k = 0; k < 4; k++) {
    int i = base + k * 256 + threadIdx.x;
    if (i < N) s += counts[i];
  }
  sdata[threadIdx.x] = s;
  __syncthreads();
  for (int off = 128; off > 0; off >>= 1) {
    if (threadIdx.x < off) sdata[threadIdx.x] += sdata[threadIdx.x + off];
    __syncthreads();
  }
  if (threadIdx.x == 0) bsum[blockIdx.x] = sdata[0];
}

__global__ __launch_bounds__(128) void k_scanpart(const int* __restrict__ bsum,
                                                  int* __restrict__ boff, int NB,
                                                  int* __restrict__ row_start, int N) {
  __shared__ int s[129];
  int t = threadIdx.x;
  s[t] = (t < NB) ? bsum[t] : 0;
  __syncthreads();
  if (t == 0) {
    int r = 0;
    for (int b = 0; b < NB; b++) { int v = s[b]; s[b] = r; r += v; }
    row_start[N] = r;  // == E
  }
  __syncthreads();
  if (t < NB) boff[t] = s[t];
}

__global__ __launch_bounds__(256) void k_scanblk(const int* __restrict__ counts,
                                                 const int* __restrict__ boff,
                                                 int* __restrict__ row_start, int N) {
  __shared__ int warp_sums[4];
  int tid = threadIdx.x, lane = tid & 63, wid = tid >> 6;
  int base = blockIdx.x * 1024;
  int i0 = base + tid * 4;
  int c0, c1, c2, c3;
  if (i0 + 3 < N) {
    int4 v = *(const int4*)(counts + i0);
    c0 = v.x; c1 = v.y; c2 = v.z; c3 = v.w;
  } else {
    c0 = (i0 + 0 < N) ? counts[i0 + 0] : 0;
    c1 = (i0 + 1 < N) ? counts[i0 + 1] : 0;
    c2 = (i0 + 2 < N) ? counts[i0 + 2] : 0;
    c3 = (i0 + 3 < N) ? counts[i0 + 3] : 0;
  }
  int s = c0 + c1 + c2 + c3;
  int incl = s;
#pragma unroll
  for (int off = 1; off < 64; off <<= 1) {
    int v = __shfl_up(incl, off);
    if (lane >= off) incl += v;
  }
  if (lane == 63) warp_sums[wid] = incl;
  __syncthreads();
  int pre = 0;
  for (int w = 0; w < wid; w++) pre += warp_sums[w];
  int run = boff[blockIdx.x] + pre + incl - s;
  if (i0 + 0 < N) row_start[i0 + 0] = run; run += c0;
  if (i0 + 1 < N) row_start[i0 + 1] = run; run += c1;
  if (i0 + 2 < N) row_start[i0 + 2] = run; run += c2;
  if (i0 + 3 < N) row_start[i0 + 3] = run;
}

__global__ __launch_bounds__(256) void k_scatter(const int* __restrict__ row,
                                                 const int* __restrict__ col,
                                                 const int* __restrict__ row_start,
                                                 int* __restrict__ cursor,
                                                 int* __restrict__ csr_col, int E) {
  int e = blockIdx.x * 256 + threadIdx.x;
  if (e < E) {
    int r = row[e];
    int pos = row_start[r] + atomicAdd(&cursor[r], 1);
    csr_col[pos] = col[e];
  }
}

// Per-node attention scalars.
__global__ __launch_bounds__(256) void k_proj(const float* __restrict__ X,
                                              const float* __restrict__ W1,
                                              const float* __restrict__ b1,
                                              const float* __restrict__ W2,
                                              const float* __restrict__ b2,
                                              const float* __restrict__ aw,
                                              const float* __restrict__ attb,
                                              float* __restrict__ s1,
                                              float* __restrict__ s2, int N) {
  int n = blockIdx.x * 256 + threadIdx.x;
  if (n >= N) return;
  float a1[16], a2[16];
#pragma unroll
  for (int h = 0; h < 16; h++) { a1[h] = b1[h]; a2[h] = b2[h]; }
  const float4* xr = (const float4*)(X + (size_t)n * 128);
  for (int d4 = 0; d4 < 32; ++d4) {
    float4 xv = xr[d4];
#pragma unroll
    for (int q = 0; q < 4; q++) {
      float xs = ((const float*)&xv)[q];
      int d = d4 * 4 + q;
      const float4* w1r = (const float4*)(W1 + d * 16);
      const float4* w2r = (const float4*)(W2 + d * 16);
#pragma unroll
      for (int g = 0; g < 4; ++g) {
        float4 wa = w1r[g], wb = w2r[g];
        a1[g * 4 + 0] += xs * wa.x; a1[g * 4 + 1] += xs * wa.y;
        a1[g * 4 + 2] += xs * wa.z; a1[g * 4 + 3] += xs * wa.w;
        a2[g * 4 + 0] += xs * wb.x; a2[g * 4 + 1] += xs * wb.y;
        a2[g * 4 + 2] += xs * wb.z; a2[g * 4 + 3] += xs * wb.w;
      }
    }
  }
  float r1 = 0.f, r2 = 0.f;
#pragma unroll
  for (int h = 0; h < 16; h++) {
    r1 += fmaxf(a1[h], 0.f) * aw[h];
    r2 += fmaxf(a2[h], 0.f) * aw[16 + h];
  }
  s1[n] = r1;
  s2[n] = r2 + attb[0];
}

// One wave per row: per-edge mask + row degree -> dis.
__global__ __launch_bounds__(256) void k_mask(const int* __restrict__ row_start,
                                              const int* __restrict__ csr_col,
                                              const float* __restrict__ s1,
                                              const float* __restrict__ s2,
                                              float* __restrict__ mask_csr,
                                              float* __restrict__ dis, int N) {
  int lane = threadIdx.x & 63, wid = threadIdx.x >> 6;
  int r = blockIdx.x * 4 + wid;
  if (r >= N) return;
  int start = row_start[r], end = row_start[r + 1];
  float s1r = s1[r];
  float sum = 0.f;
  for (int p = start + lane; p < end; p += 64) {
    int c = csr_col[p];
    float logit = s1r + s2[c];
    float g = 1.f / (1.f + __expf(-logit));
    float m = fminf(fmaxf(fmaf(g, 1.2f, -0.1f), 0.f), 1.f);
    mask_csr[p] = m;
    sum += m;
  }
#pragma unroll
  for (int off = 32; off > 0; off >>= 1) sum += __shfl_down(sum, off);
  if (lane == 0) dis[r] = rsqrtf(sum + 1.0f);
}

// Hs = bf16x2( dis[n] * (X @ W)[n,:] ).  64-row tile, W+X staged in LDS.
template <int DOUT>
__global__ __launch_bounds__(256) void k_gemm(const float* __restrict__ X,
                                              const float* __restrict__ W,
                                              const float* __restrict__ dis,
                                              uint32_t* __restrict__ Hs, int N) {
  constexpr int CPT = DOUT / 4;  // cols per thread
  __shared__ float Ws[64 * DOUT];
  __shared__ float Xs[64][68];
  int tid = threadIdx.x;
  int n0 = blockIdx.x * 64;
  int nl = tid >> 2, cq = tid & 3;
  int nvalid = min(64, N - n0);
  float acc[CPT];
#pragma unroll
  for (int j = 0; j < CPT; j++) acc[j] = 0.f;
  for (int dt = 0; dt < 2; ++dt) {
    __syncthreads();
    const float4* Wg = (const float4*)(W + dt * 64 * DOUT);
    float4* Ws4 = (float4*)Ws;
    for (int i = tid; i < 64 * DOUT / 4; i += 256) Ws4[i] = Wg[i];
    for (int i = tid; i < nvalid * 16; i += 256) {
      int rl = i >> 4, d4 = i & 15;
      float4 v = *(const float4*)(X + (size_t)(n0 + rl) * 128 + dt * 64 + d4 * 4);
      Xs[rl][d4 * 4 + 0] = v.x; Xs[rl][d4 * 4 + 1] = v.y;
      Xs[rl][d4 * 4 + 2] = v.z; Xs[rl][d4 * 4 + 3] = v.w;
    }
    __syncthreads();
#pragma unroll 8
    for (int d = 0; d < 64; ++d) {
      float xv = Xs[nl][d];
#pragma unroll
      for (int jj = 0; jj < CPT / 4; ++jj) {
        const float4 w = *(const float4*)&Ws[d * DOUT + (cq + jj * 4) * 4];
        acc[jj * 4 + 0] = fmaf(xv, w.x, acc[jj * 4 + 0]);
        acc[jj * 4 + 1] = fmaf(xv, w.y, acc[jj * 4 + 1]);
        acc[jj * 4 + 2] = fmaf(xv, w.z, acc[jj * 4 + 2]);
        acc[jj * 4 + 3] = fmaf(xv, w.w, acc[jj * 4 + 3]);
      }
    }
  }
  int n = n0 + nl;
  if (n < N) {
    float d = dis[n];
    uint32_t* Hr = Hs + (size_t)n * (DOUT / 2);
#pragma unroll
    for (int jj = 0; jj < CPT / 4; jj++) {
      uint2 o;
      o.x = pack_bf2(d * acc[jj * 4 + 0], d * acc[jj * 4 + 1]);
      o.y = pack_bf2(d * acc[jj * 4 + 2], d * acc[jj * 4 + 3]);
      *(uint2*)&Hr[(cq + jj * 4) * 2] = o;
    }
  }
}

// One wave per row, lanes split into edge-groups:
//   LPE = DOUT/4 lanes per edge (uint2 = 4 bf16 feats/lane), EPI = 64/LPE edges/iter.
// out[r] = act( dis[r] * ( sum_e mask_e * Hs[col_e] + Hs[r] ) ).
template <int DOUT, bool RELU>
__global__ __launch_bounds__(256) void k_agg(const int* __restrict__ rs,
                                             const int* __restrict__ csr_col,
                                             const float* __restrict__ mask,
                                             const float* __restrict__ dis,
                                             const uint32_t* __restrict__ Hs,
                                             float* __restrict__ out, int N) {
  constexpr int LPE = DOUT / 4;
  constexpr int EPI = 64 / LPE;
  int lane = threadIdx.x & 63, wid = threadIdx.x >> 6;
  int r = blockIdx.x * 4 + wid;
  if (r >= N) return;
  int start = rs[r], end = rs[r + 1];
  int sub = lane / LPE;
  int fl = lane & (LPE - 1);
  float a0 = 0.f, a1 = 0.f, a2 = 0.f, a3 = 0.f;
  {  // self term (mask == 1), only in group 0
    uint2 u = *(const uint2*)(Hs + (size_t)r * (DOUT / 2) + fl * 2);
    if (sub == 0) { a0 = bf_lo(u.x); a1 = bf_hi(u.x); a2 = bf_lo(u.y); a3 = bf_hi(u.y); }
  }
  int p = start;
  for (; p + 2 * EPI <= end; p += 2 * EPI) {
    int eA = p + sub, eB = p + EPI + sub;
    int cA = csr_col[eA], cB = csr_col[eB];
    float mA = mask[eA], mB = mask[eB];
    uint2 uA = *(const uint2*)(Hs + (size_t)cA * (DOUT / 2) + fl * 2);
    uint2 uB = *(const uint2*)(Hs + (size_t)cB * (DOUT / 2) + fl * 2);
    a0 = fmaf(mA, bf_lo(uA.x), a0); a1 = fmaf(mA, bf_hi(uA.x), a1);
    a2 = fmaf(mA, bf_lo(uA.y), a2); a3 = fmaf(mA, bf_hi(uA.y), a3);
    a0 = fmaf(mB, bf_lo(uB.x), a0); a1 = fmaf(mB, bf_hi(uB.x), a1);
    a2 = fmaf(mB, bf_lo(uB.y), a2); a3 = fmaf(mB, bf_hi(uB.y), a3);
  }
  for (; p < end; p += EPI) {
    int e = p + sub;
    bool v = e < end;
    int c = v ? csr_col[e] : r;
    float m = v ? mask[e] : 0.f;
    uint2 u = *(const uint2*)(Hs + (size_t)c * (DOUT / 2) + fl * 2);
    a0 = fmaf(m, bf_lo(u.x), a0); a1 = fmaf(m, bf_hi(u.x), a1);
    a2 = fmaf(m, bf_lo(u.y), a2); a3 = fmaf(m, bf_hi(u.y), a3);
  }
#pragma unroll
  for (int off = LPE; off < 64; off <<= 1) {
    a0 += __shfl_xor(a0, off); a1 += __shfl_xor(a1, off);
    a2 += __shfl_xor(a2, off); a3 += __shfl_xor(a3, off);
  }
  if (lane < LPE) {
    float dr = dis[r];
    float4 o = make_float4(dr * a0, dr * a1, dr * a2, dr * a3);
    if (RELU) {
      o.x = fmaxf(o.x, 0.f); o.y = fmaxf(o.y, 0.f);
      o.z = fmaxf(o.z, 0.f); o.w = fmaxf(o.w, 0.f);
    }
    *(float4*)(out + (size_t)r * DOUT + fl * 4) = o;
  }
}

extern "C" void kernel_launch(void* const* d_in, const int* in_sizes, int n_in,
                              void* d_out, int out_size, void* d_ws, size_t ws_size,
                              hipStream_t stream) {
  const float* x      = (const float*)d_in[0];
  const int*   row    = (const int*)d_in[1];
  const int*   col    = (const int*)d_in[2];
  const float* nb_w   = (const float*)d_in[3];
  const float* nb_b   = (const float*)d_in[4];
  const float* self_w = (const float*)d_in[5];
  const float* self_b = (const float*)d_in[6];
  const float* att_w  = (const float*)d_in[7];
  const float* att_b  = (const float*)d_in[8];
  const float* w0     = (const float*)d_in[9];
  const float* w1     = (const float*)d_in[10];
  float* out = (float*)d_out;

  const int N = in_sizes[0] / 128;
  const int E = in_sizes[1];

  char* p = (char*)d_ws;
  auto alloc = [&](size_t bytes) -> void* {
    void* q = (void*)p;
    p += (bytes + 255) & ~(size_t)255;
    return q;
  };
  int*      counts    = (int*)alloc((size_t)N * 4);   // also scatter cursor
  int*      row_start = (int*)alloc((size_t)(N + 1) * 4);
  int*      bsum      = (int*)alloc(512);
  int*      boff      = (int*)alloc(512);
  int*      csr_col   = (int*)alloc((size_t)E * 4);
  float*    mask_csr  = (float*)alloc((size_t)E * 4);
  float*    s1        = (float*)alloc((size_t)N * 4);
  float*    s2        = (float*)alloc((size_t)N * 4);
  float*    dis       = (float*)alloc((size_t)N * 4);
  uint32_t* hs        = (uint32_t*)alloc((size_t)N * 64 * 4);  // bf16x2, up to 128 feats
  float*    X1        = (float*)alloc((size_t)N * 128 * 4);

  const int NB = (N + 1023) / 1024;
  const int gE = (E + 255) / 256;
  const int gw = (N + 3) / 4;
  const int gp = (N + 255) / 256;
  const int gg = (N + 63) / 64;

  // ---- CSR build ----
  hipMemsetAsync(counts, 0, (size_t)N * 4, stream);
  k_hist<<<gE, 256, 0, stream>>>(row, counts, E);
  k_blocksum<<<NB, 256, 0, stream>>>(counts, bsum, N);
  k_scanpart<<<1, 128, 0, stream>>>(bsum, boff, NB, row_start, N);
  k_scanblk<<<NB, 256, 0, stream>>>(counts, boff, row_start, N);
  hipMemsetAsync(counts, 0, (size_t)N * 4, stream);
  k_scatter<<<gE, 256, 0, stream>>>(row, col, row_start, counts, csr_col, E);

  // ---- layer 0: din=128, dout=128, relu ----
  k_proj<<<gp, 256, 0, stream>>>(x, nb_w, nb_b, self_w, self_b, att_w, att_b, s1, s2, N);
  k_mask<<<gw, 256, 0, stream>>>(row_start, csr_col, s1, s2, mask_csr, dis, N);
  k_gemm<128><<<gg, 256, 0, stream>>>(x, w0, dis, hs, N);
  k_agg<128, true><<<gw, 256, 0, stream>>>(row_start, csr_col, mask_csr, dis, hs, X1, N);

  // ---- layer 1: din=128, dout=64, identity ----
  k_proj<<<gp, 256, 0, stream>>>(X1, nb_w + 2048, nb_b + 16, self_w + 2048, self_b + 16,
                                 att_w + 32, att_b + 1, s1, s2, N);
  k_mask<<<gw, 256, 0, stream>>>(row_start, csr_col, s1, s2, mask_csr, dis, N);
  k_gemm<64><<<gg, 256, 0, stream>>>(X1, w1, dis, hs, N);
  k_agg<64, false><<<gw, 256, 0, stream>>>(row_start, csr_col, mask_csr, dis, hs, out, N);
}